// Round 3
// baseline (444.397 us; speedup 1.0000x reference)
//
#include <hip/hip_runtime.h>

// ViewMorphing forward — MI355X (gfx950)
// out[0 .. 3*N*HW-1] = warped+masked image sum, out[3*N*HW] = oob loss scalar.
//
// R1/R2: 4 pixels/thread (float4 C/M loads + float4 stores), y-tap pairs
// fetched as one dwordx2 each -> ~2.3x fewer VMEM instrs than R0.
// R2 fix: use clang ext_vector float4 for nontemporal builtins (HIP float4
// is a struct and is rejected).

constexpr int D    = 512;
constexpr int HW   = D * D;            // 2^18
constexpr int NB   = 32;
constexpr int NPIX = NB * HW;          // 8,388,608
constexpr float LOSS_SCALE = (float)(0.01 / (2.0 * (double)NPIX * (double)HW));

// native clang vectors (accepted by nontemporal builtins)
typedef float f4  __attribute__((ext_vector_type(4)));
typedef float f2a4 __attribute__((ext_vector_type(2), aligned(4)));

__device__ __forceinline__ f2a4 ld2(const float* p) {
    return *(const f2a4*)p;
}

// One bilinear sample of a 3-channel image (channel-planar), accumulated with mask m.
__device__ __forceinline__ void sample_add(const float* __restrict__ im,
                                           float q0o, float q1o, float m,
                                           float& oob, float& ax, float& ay, float& az)
{
    const float hi = 510.999f;   // D - 1.001
    float q0 = fminf(fmaxf(q0o, 0.001f), hi);
    float q1 = fminf(fmaxf(q1o, 0.001f), hi);
    float d0 = q0o - q0, d1 = q1o - q1;
    oob += d0 * d0 + d1 * d1;

    float fx = floorf(q0), cx = ceilf(q0);
    float fy = floorf(q1), cy = ceilf(q1);
    // reference weights: w = (1-|q0-nbx|)*(1-|q1-nby|); integral coord -> both taps weight 1
    float wfx = 1.0f - (q0 - fx), wcx = 1.0f - (cx - q0);
    float wfy = 1.0f - (q1 - fy), wcy = 1.0f - (cy - q1);

    int ix0 = (int)fx, ix1 = (int)cx, iy0 = (int)fy;
    bool ysame = ((int)cy == iy0);          // q1 integral -> ceil tap == floor tap

    int off0 = (ix0 << 9) + iy0;            // ind = y + D*x
    int off1 = (ix1 << 9) + iy0;

    f2a4 r0x = ld2(im + off0);
    f2a4 r1x = ld2(im + off1);
    f2a4 r0y = ld2(im + HW + off0);
    f2a4 r1y = ld2(im + HW + off1);
    f2a4 r0z = ld2(im + 2 * HW + off0);
    f2a4 r1z = ld2(im + 2 * HW + off1);

    float v0, v1;
    v0 = ysame ? r0x.x : r0x.y;  v1 = ysame ? r1x.x : r1x.y;
    ax += m * (wfx * (wfy * r0x.x + wcy * v0) + wcx * (wfy * r1x.x + wcy * v1));
    v0 = ysame ? r0y.x : r0y.y;  v1 = ysame ? r1y.x : r1y.y;
    ay += m * (wfx * (wfy * r0y.x + wcy * v0) + wcx * (wfy * r1y.x + wcy * v1));
    v0 = ysame ? r0z.x : r0z.y;  v1 = ysame ? r1z.x : r1z.y;
    az += m * (wfx * (wfy * r0z.x + wcy * v0) + wcx * (wfy * r1z.x + wcy * v1));
}

__global__ void __launch_bounds__(256)
vm_fwd(const float* __restrict__ im1, const float* __restrict__ im2,
       const float* __restrict__ C,   const float* __restrict__ M1,
       const float* __restrict__ M2,  float* __restrict__ out)
{
    int tid = blockIdx.x * 256 + threadIdx.x;   // 0 .. NPIX/4 - 1
    int pix = tid << 2;                          // base pixel (quad never crosses a row)
    int n   = pix >> 18;
    int hw  = pix & (HW - 1);
    float qx  = (float)(hw >> 9);        // row coord
    float qyb = (float)(hw & (D - 1));   // col coord of lane's first pixel

    const float* Cn = C + (size_t)n * 2 * HW;
    f4 c0v = __builtin_nontemporal_load((const f4*)(Cn + hw));
    f4 c1v = __builtin_nontemporal_load((const f4*)(Cn + HW + hw));
    f4 m1v = __builtin_nontemporal_load((const f4*)(M1 + pix));
    f4 m2v = __builtin_nontemporal_load((const f4*)(M2 + pix));

    const float* p1 = im1 + (size_t)n * 3 * HW;
    const float* p2 = im2 + (size_t)n * 3 * HW;

    float oob = 0.0f;
    f4 ox, oy, oz;
    #pragma unroll
    for (int j = 0; j < 4; ++j) {
        float qy = qyb + (float)j;
        float ax = 0.f, ay = 0.f, az = 0.f;
        sample_add(p1, qx + c0v[j], qy + c1v[j], m1v[j], oob, ax, ay, az);
        sample_add(p2, qx - c0v[j], qy - c1v[j], m2v[j], oob, ax, ay, az);
        ox[j] = ax; oy[j] = ay; oz[j] = az;
    }

    size_t obase = (size_t)n * 3 * HW + hw;
    __builtin_nontemporal_store(ox, (f4*)(out + obase));
    __builtin_nontemporal_store(oy, (f4*)(out + obase + HW));
    __builtin_nontemporal_store(oz, (f4*)(out + obase + 2 * HW));

    // block-level reduction of oob, then one atomic per block
    #pragma unroll
    for (int off = 32; off > 0; off >>= 1)
        oob += __shfl_down(oob, off, 64);

    __shared__ float wave_sums[4];
    int lane = threadIdx.x & 63;
    int wave = threadIdx.x >> 6;
    if (lane == 0) wave_sums[wave] = oob;
    __syncthreads();
    if (threadIdx.x == 0) {
        float s = wave_sums[0] + wave_sums[1] + wave_sums[2] + wave_sums[3];
        atomicAdd(out + (size_t)3 * NPIX, s * LOSS_SCALE);
    }
}

extern "C" void kernel_launch(void* const* d_in, const int* in_sizes, int n_in,
                              void* d_out, int out_size, void* d_ws, size_t ws_size,
                              hipStream_t stream) {
    const float* im1 = (const float*)d_in[0];
    const float* im2 = (const float*)d_in[1];
    const float* C   = (const float*)d_in[2];
    const float* M1  = (const float*)d_in[3];
    const float* M2  = (const float*)d_in[4];
    float* out = (float*)d_out;

    // zero the loss scalar (harness poisons d_out with 0xAA before every launch)
    (void)hipMemsetAsync(out + (size_t)3 * NPIX, 0, sizeof(float), stream);

    // NPIX/4 threads = 2,097,152 -> exactly 8192 blocks of 256
    vm_fwd<<<NPIX / 4 / 256, 256, 0, stream>>>(im1, im2, C, M1, M2, out);
}